// Round 2
// baseline (2845.685 us; speedup 1.0000x reference)
//
#include <hip/hip_runtime.h>
#include <cstdint>
#include <math.h>

// Problem constants
#define NBATCH 32
#define NSQ 1024
#define NCQ 1024
#define DDIM 256
#define DP 257
#define KQ 128
#define KP 129

// ---------------- device helpers ----------------
__device__ __forceinline__ float artanh_clip(float x) {
    x = fminf(fmaxf(x, -1.0f + 1e-5f), 1.0f - 1e-5f);
    return 0.5f * (log1pf(x) - log1pf(-x));
}
__device__ __forceinline__ float gelu_f(float x) {
    return 0.5f * x * (1.0f + erff(x * 0.70710678118654752440f));
}
__device__ __forceinline__ float waveRedSum(float v) {
#pragma unroll
    for (int o = 32; o > 0; o >>= 1) v += __shfl_down(v, o, 64);
    return __shfl(v, 0, 64);
}
__device__ __forceinline__ float blockRedSum(float v, float* buf) {
    int lane = threadIdx.x & 63, wid = threadIdx.x >> 6;
#pragma unroll
    for (int o = 32; o > 0; o >>= 1) v += __shfl_down(v, o, 64);
    __syncthreads();
    if (lane == 0) buf[wid] = v;
    __syncthreads();
    int nw = blockDim.x >> 6;
    float s = buf[0];
    for (int i = 1; i < nw; i++) s += buf[i];
    return s;
}
__device__ __forceinline__ float blockRedMax(float v, float* buf) {
    int lane = threadIdx.x & 63, wid = threadIdx.x >> 6;
#pragma unroll
    for (int o = 32; o > 0; o >>= 1) v = fmaxf(v, __shfl_down(v, o, 64));
    __syncthreads();
    if (lane == 0) buf[wid] = v;
    __syncthreads();
    int nw = blockDim.x >> 6;
    float s = buf[0];
    for (int i = 1; i < nw; i++) s = fmaxf(s, buf[i]);
    return s;
}

// ---------------- generic tiled fp32 GEMM ----------------
// C[m,n] (+)= sum_k A[m,k]*B[k,n] (+bias[n])
// AT=false: A[m,k] at A + m*lda + k ; AT=true: A + k*lda + m
// BT=false: B[k,n] at B + k*ldb + n ; BT=true: B + n*ldb + k
template <bool AT, bool BT, bool ACC>
__global__ __launch_bounds__(256) void gemm_tile(
    const float* __restrict__ A, int lda, int64_t sA,
    const float* __restrict__ B, int ldb, int64_t sB,
    float* __restrict__ C, int ldc, int64_t sC,
    const float* __restrict__ bias, int M, int N, int Kd)
{
    __shared__ float As[16][68];
    __shared__ float Bs[16][68];
    A += (int64_t)blockIdx.z * sA;
    B += (int64_t)blockIdx.z * sB;
    C += (int64_t)blockIdx.z * sC;
    const int m0 = blockIdx.y * 64, n0 = blockIdx.x * 64;
    const int t = threadIdx.x;
    const int tm = t & 15, tn = t >> 4;
    const bool alA = ((lda & 3) == 0) && ((((size_t)A) & 15) == 0);
    const bool alB = ((ldb & 3) == 0) && ((((size_t)B) & 15) == 0);
    float acc[4][4] = {{0.f}};
    for (int k0 = 0; k0 < Kd; k0 += 16) {
        // A tile -> As[k][m]
        if (!AT) {
            int m = t >> 2, k4 = (t & 3) * 4;
            int gm = m0 + m;
            const float* ap = A + (int64_t)gm * lda + k0 + k4;
            bool mok = gm < M;
            if (alA && mok && (k0 + 16 <= Kd)) {
                float4 av = *(const float4*)ap;
                As[k4 + 0][m] = av.x; As[k4 + 1][m] = av.y;
                As[k4 + 2][m] = av.z; As[k4 + 3][m] = av.w;
            } else {
#pragma unroll
                for (int i = 0; i < 4; i++)
                    As[k4 + i][m] = (mok && (k0 + k4 + i) < Kd) ? ap[i] : 0.0f;
            }
        } else {
            int m = t & 63, kb = t >> 6;
            int gm = m0 + m;
#pragma unroll
            for (int p = 0; p < 4; p++) {
                int kk = kb + p * 4;
                int gk = k0 + kk;
                As[kk][m] = (gm < M && gk < Kd) ? A[(int64_t)gk * lda + gm] : 0.0f;
            }
        }
        // B tile -> Bs[k][n]
        if (!BT) {
            int kk = t >> 4, n4 = (t & 15) * 4;
            int gn = n0 + n4;
            const float* bp = B + (int64_t)(k0 + kk) * ldb + gn;
            bool kok = (k0 + kk) < Kd;
            if (alB && kok && (gn + 4 <= N)) {
                *(float4*)&Bs[kk][n4] = *(const float4*)bp;
            } else {
#pragma unroll
                for (int i = 0; i < 4; i++)
                    Bs[kk][n4 + i] = (kok && (gn + i) < N) ? bp[i] : 0.0f;
            }
        } else {
            int n = t >> 2, k4 = (t & 3) * 4;
            int gn = n0 + n;
            const float* bp = B + (int64_t)gn * ldb + k0 + k4;
            bool nok = gn < N;
            if (alB && nok && (k0 + 16 <= Kd)) {
                float4 bv = *(const float4*)bp;
                Bs[k4 + 0][n] = bv.x; Bs[k4 + 1][n] = bv.y;
                Bs[k4 + 2][n] = bv.z; Bs[k4 + 3][n] = bv.w;
            } else {
#pragma unroll
                for (int i = 0; i < 4; i++)
                    Bs[k4 + i][n] = (nok && (k0 + k4 + i) < Kd) ? bp[i] : 0.0f;
            }
        }
        __syncthreads();
#pragma unroll
        for (int kk = 0; kk < 16; kk++) {
            float4 a = *(const float4*)&As[kk][tm * 4];
            float4 b = *(const float4*)&Bs[kk][tn * 4];
            acc[0][0] += a.x * b.x; acc[0][1] += a.x * b.y; acc[0][2] += a.x * b.z; acc[0][3] += a.x * b.w;
            acc[1][0] += a.y * b.x; acc[1][1] += a.y * b.y; acc[1][2] += a.y * b.z; acc[1][3] += a.y * b.w;
            acc[2][0] += a.z * b.x; acc[2][1] += a.z * b.y; acc[2][2] += a.z * b.z; acc[2][3] += a.z * b.w;
            acc[3][0] += a.w * b.x; acc[3][1] += a.w * b.y; acc[3][2] += a.w * b.z; acc[3][3] += a.w * b.w;
        }
        __syncthreads();
    }
#pragma unroll
    for (int i = 0; i < 4; i++) {
        int row = m0 + tm * 4 + i;
        if (row >= M) continue;
        float* cp = C + (int64_t)row * ldc;
#pragma unroll
        for (int j = 0; j < 4; j++) {
            int col = n0 + tn * 4 + j;
            if (col < N) {
                float v = acc[i][j];
                if (bias) v += bias[col];
                if (ACC) cp[col] += v; else cp[col] = v;
            }
        }
    }
}

// ---------------- DFT matrix generation ----------------
__global__ void gendft_kernel(float* Cm, float* Sm, int N, float signS) {
    int idx = blockIdx.x * 256 + threadIdx.x;
    int k = idx / N;
    int n = idx - k * N;
    int p = (k * n) & (N - 1);
    float ang = (6.28318530717958647692f / (float)N) * (float)p;
    Cm[idx] = cosf(ang);
    Sm[idx] = signS * sinf(ang);
}

// ---------------- rowwise kernels ----------------
// p_logmap0 over rows of 256
__global__ __launch_bounds__(256) void plog_kernel(const float* __restrict__ in, float* __restrict__ outp) {
    __shared__ float red[4];
    int64_t row = blockIdx.x; int t = threadIdx.x;
    float v = in[row * 256 + t];
    float s = blockRedSum(v * v, red);
    float yn = sqrtf(fmaxf(s, 1e-15f));
    float fac = artanh_clip(yn) / yn;
    outp[row * 256 + t] = fac * v;
}

// euclid_to_lorentz: rows of 256 -> rows of 257
__global__ __launch_bounds__(256) void e2l_kernel(const float* __restrict__ in, float* __restrict__ outp) {
    __shared__ float red[4];
    int64_t row = blockIdx.x; int t = threadIdx.x;
    float v = in[row * 256 + t];
    float s = blockRedSum(v * v, red);
    float xn = sqrtf(fmaxf(s, 1e-15f)) + 1e-5f;
    float sc = fminf(1.0f, 2.0f / xn);
    float xs = v * sc;
    float s2 = fmaxf(s * sc * sc, 1e-15f);
    float vn = sqrtf(s2);
    float fac = sinhf(vn) / vn;
    float* o = outp + row * DP;
    if (t == 0) o[0] = coshf(vn);
    o[1 + t] = fac * xs;
}

// lorentz_linear time fixup, in-place, rows of 257
__global__ __launch_bounds__(256) void lfix_kernel(float* __restrict__ y) {
    __shared__ float red[4];
    int64_t row = blockIdx.x; int t = threadIdx.x;
    float* r = y + row * DP;
    float v = r[1 + t];
    float s = blockRedSum(v * v, red);
    if (t == 0) r[0] = sqrtf(s + 1.0f);
}

// lorentz_linear(129) + lorentz_to_poincare: rows 129 -> 128
__global__ __launch_bounds__(128) void poinc_kernel(const float* __restrict__ y, float* __restrict__ outp) {
    __shared__ float red[2];
    int64_t row = blockIdx.x; int t = threadIdx.x;
    const float* r = y + row * KP;
    float v = r[1 + t];
    float s = blockRedSum(v * v, red);
    float tim = sqrtf(s + 1.0f);
    outp[row * KQ + t] = v / (tim + 1.0f);
}

// lorentz_act on Lmat rows (1024), in-place, + row norms
__global__ __launch_bounds__(256) void lact_kernel(float* __restrict__ Lmat, float* __restrict__ xnrow) {
    __shared__ float red[4];
    int64_t row = blockIdx.x; int t = threadIdx.x;
    float* r = Lmat + row * (int64_t)NCQ;
    float g[4]; float s = 0.f;
#pragma unroll
    for (int i = 0; i < 4; i++) {
        int idx = t + 256 * i;
        float v = r[idx];
        if (idx > 0) { g[i] = gelu_f(v); s += g[i] * g[i]; } else g[i] = 0.f;
    }
    s = blockRedSum(s, red);
#pragma unroll
    for (int i = 0; i < 4; i++) { int idx = t + 256 * i; if (idx > 0) r[idx] = g[i]; }
    if (t == 0) {
        r[0] = sqrtf(1.0f + s);
        xnrow[row] = sqrtf(fmaxf(1.0f + 2.0f * s, 1e-15f));
    }
}

// column norms of Lmat (norm over n for each (b,m))
__global__ __launch_bounds__(256) void colnorm_kernel(const float* __restrict__ Lmat, float* __restrict__ xncol) {
    int b = blockIdx.x; int m = blockIdx.y * 256 + threadIdx.x;
    const float* base = Lmat + (int64_t)b * NSQ * NCQ + m;
    float s = 0.f;
    for (int n = 0; n < NSQ; n++) { float v = base[n * NCQ]; s += v * v; }
    xncol[b * NCQ + m] = sqrtf(fmaxf(s, 1e-15f));
}

// Hs path: per-(b,n) row ops over K=128, emits softmax logit
__global__ __launch_bounds__(64) void rowops_s_kernel(
    const float* __restrict__ Hsa, const float* __restrict__ mxs,
    const float* __restrict__ xnrow, const float* __restrict__ whs,
    float* __restrict__ logits)
{
    int64_t row = blockIdx.x; int t = threadIdx.x;
    const float* p = Hsa + row * KQ;
    const float* q = mxs + row * KQ;
    float p0 = p[t], p1 = p[t + 64], q0 = q[t], q1 = q[t + 64];
    float mxn = sqrtf(fmaxf(waveRedSum(q0 * q0 + q1 * q1), 1e-15f));
    float xn = xnrow[row];
    float fac = tanhf(mxn / xn * artanh_clip(xn)) / mxn;
    float y0 = fac * q0, y1 = fac * q1;
    float xy = waveRedSum(p0 * y0 + p1 * y1);
    float x2 = waveRedSum(p0 * p0 + p1 * p1);
    float y2 = waveRedSum(y0 * y0 + y1 * y1);
    float ca = 1.f + 2.f * xy + y2, cb = 1.f - x2;
    float den = fmaxf(1.f + 2.f * xy + x2 * y2, 1e-15f);
    float h0 = (ca * p0 + cb * y0) / den, h1 = (ca * p1 + cb * y1) / den;
    float hn = sqrtf(fmaxf(waveRedSum(h0 * h0 + h1 * h1), 1e-15f));
    float uf = artanh_clip(hn) / hn;
    float g0 = gelu_f(uf * h0), g1 = gelu_f(uf * h1);
    float gn = sqrtf(fmaxf(waveRedSum(g0 * g0 + g1 * g1), 1e-15f));
    float ef = tanhf(gn) / gn;
    float H0 = ef * g0, H1 = ef * g1;
    float dot = waveRedSum(H0 * whs[t] + H1 * whs[t + 64]);
    float Hn = sqrtf(fmaxf(waveRedSum(H0 * H0 + H1 * H1), 1e-15f));
    float mxn2 = sqrtf(fmaxf(dot * dot, 1e-15f));
    float lg = tanhf(mxn2 / Hn * artanh_clip(Hn)) * dot / mxn2;
    if (t == 0) logits[row] = lg;
}

// mobius_matvec scale on mx_cT columns (per (b,m), reduce over j=0..127)
__global__ __launch_bounds__(256) void colscale_kernel(float* __restrict__ mxcT, const float* __restrict__ xncol) {
    int b = blockIdx.x; int m = blockIdx.y * 256 + threadIdx.x;
    float* base = mxcT + (int64_t)b * KQ * NCQ + m;
    float s = 0.f;
    for (int j = 0; j < KQ; j++) { float v = base[j * NCQ]; s += v * v; }
    float mxn = sqrtf(fmaxf(s, 1e-15f));
    float xn = xncol[b * NCQ + m];
    float fac = tanhf(mxn / xn * artanh_clip(xn)) / mxn;
    for (int j = 0; j < KQ; j++) base[j * NCQ] *= fac;
}

// Hc path: per-(b,k) row ops over NC=1024; x read strided from HcA (B,NC,K);
// y holds Hc_b^T in, Hc out (in place, layout B,K,NC)
__global__ __launch_bounds__(256) void rowops_c_kernel(const float* __restrict__ HcA, float* __restrict__ y) {
    __shared__ float red[4];
    int64_t row = blockIdx.x;
    int b = (int)(row >> 7), k = (int)(row & 127);
    const float* xbase = HcA + (int64_t)b * NCQ * KQ + k;  // x[m] = xbase[m*KQ]
    float* yr = y + row * (int64_t)NCQ;
    int t = threadIdx.x;
    float xv[4], yv[4];
    float xy = 0.f, x2 = 0.f, y2 = 0.f;
#pragma unroll
    for (int i = 0; i < 4; i++) {
        int m = t + 256 * i;
        xv[i] = xbase[(int64_t)m * KQ]; yv[i] = yr[m];
        xy += xv[i] * yv[i]; x2 += xv[i] * xv[i]; y2 += yv[i] * yv[i];
    }
    xy = blockRedSum(xy, red);
    x2 = blockRedSum(x2, red);
    y2 = blockRedSum(y2, red);
    float ca = 1.f + 2.f * xy + y2, cb = 1.f - x2;
    float den = fmaxf(1.f + 2.f * xy + x2 * y2, 1e-15f);
    float h[4]; float hn2 = 0.f;
#pragma unroll
    for (int i = 0; i < 4; i++) { h[i] = (ca * xv[i] + cb * yv[i]) / den; hn2 += h[i] * h[i]; }
    hn2 = blockRedSum(hn2, red);
    float hn = sqrtf(fmaxf(hn2, 1e-15f));
    float uf = artanh_clip(hn) / hn;
    float g[4]; float gn2 = 0.f;
#pragma unroll
    for (int i = 0; i < 4; i++) { g[i] = gelu_f(uf * h[i]); gn2 += g[i] * g[i]; }
    gn2 = blockRedSum(gn2, red);
    float gn = sqrtf(fmaxf(gn2, 1e-15f));
    float ef = tanhf(gn) / gn;
#pragma unroll
    for (int i = 0; i < 4; i++) yr[t + 256 * i] = ef * g[i];
}

// Ac logits: per (b,n) reduce over k of Hc (B,K,NC layout)
__global__ __launch_bounds__(256) void logitsc_kernel(const float* __restrict__ Hc, const float* __restrict__ whc, float* __restrict__ lgc) {
    int b = blockIdx.x; int m = blockIdx.y * 256 + threadIdx.x;
    const float* base = Hc + (int64_t)b * KQ * NCQ + m;
    float s1 = 0.f, s2 = 0.f;
    for (int j = 0; j < KQ; j++) { float v = base[j * NCQ]; s1 += v * whc[j]; s2 += v * v; }
    float xn = sqrtf(fmaxf(s2, 1e-15f));
    float mxn = sqrtf(fmaxf(s1 * s1, 1e-15f));
    lgc[b * NCQ + m] = tanhf(mxn / xn * artanh_clip(xn)) * s1 / mxn;
}

// softmax over 1024 per batch
__global__ __launch_bounds__(256) void softmax_kernel(const float* __restrict__ lg, float* __restrict__ outp) {
    __shared__ float red[4];
    int b = blockIdx.x; int t = threadIdx.x;
    const float* x = lg + b * 1024;
    float v[4]; float m = -1e30f;
#pragma unroll
    for (int i = 0; i < 4; i++) { v[i] = x[t + 256 * i]; m = fmaxf(m, v[i]); }
    m = blockRedMax(m, red);
    float s = 0.f;
#pragma unroll
    for (int i = 0; i < 4; i++) { v[i] = expf(v[i] - m); s += v[i]; }
    s = blockRedSum(s, red);
    float inv = 1.0f / s;
#pragma unroll
    for (int i = 0; i < 4; i++) outp[b * 1024 + t + 256 * i] = v[i] * inv;
}

// centroid numerator: avg[b,d] = sum_n w[b,n] * L[b,n,d]
__global__ __launch_bounds__(320) void centroid_kernel(
    const float* __restrict__ Ls, const float* __restrict__ Lc,
    const float* __restrict__ As, const float* __restrict__ Ac,
    float* __restrict__ co_s, float* __restrict__ co_c)
{
    int b = blockIdx.x;
    bool which = blockIdx.y != 0;
    const float* L = which ? Lc : Ls;
    const float* w = which ? Ac : As;
    float* o = which ? co_c : co_s;
    int t = threadIdx.x;
    if (t >= DP) return;
    const float* Lb = L + (int64_t)b * NSQ * DP + t;
    const float* wb = w + b * NSQ;
    float s = 0.f;
    for (int n = 0; n < NSQ; n++) s += wb[n] * Lb[(int64_t)n * DP];
    o[b * DP + t] = s;
}

// normalize centroids, lorentz_concat, write co_sc
__global__ __launch_bounds__(256) void final_kernel(const float* __restrict__ co_s, const float* __restrict__ co_c, float* __restrict__ outp) {
    __shared__ float red[4];
    int b = blockIdx.x, t = threadIdx.x;
    float zmine[2];
    for (int w = 0; w < 2; w++) {
        const float* co = (w ? co_c : co_s) + b * DP;
        float at = co[0];
        float asp = co[1 + t];
        float ssp = blockRedSum(asp * asp, red);
        float li = ssp - at * at;              // l_inner(avg,avg)
        float den = sqrtf(fmaxf(fabsf(li), 1e-8f));
        float xt = at / den, xsp = asp / den;
        float s2 = blockRedSum(xsp * xsp, red);
        float nrm = sqrtf(fmaxf(s2, 1e-15f));
        float ac = acoshf(fmaxf(xt, 1.0f + 1e-7f));
        zmine[w] = ac * xsp / nrm;
    }
    float vn2 = blockRedSum(zmine[0] * zmine[0] + zmine[1] * zmine[1], red);
    float vn = sqrtf(fmaxf(vn2, 1e-15f));
    float sc = sinhf(vn) / vn;
    if (t == 0) outp[b * 513] = coshf(vn);
    outp[b * 513 + 1 + t] = sc * zmine[0];
    outp[b * 513 + 1 + 256 + t] = sc * zmine[1];
}

// ---------------- host launcher ----------------
// Workspace plan (floats), total 63,193,152 fl = 241.1 MiB:
//   R_big  33,554,432 : FFT staging S1|S2|S3 (25.17M) -> Lmat (33.55M)
//   Ls      8,421,376 : persistent
//   Lc      8,421,376 : persistent
//   R_A     8,421,376 : DFT mats (2.23M) -> Llin (8.42M) -> HsA|HcA (8.39M)
//   R_B     4,227,072 : ytmp (4.23M) -> mx_s (4.19M) -> mx_cT/Hc (4.19M)
//   smalls    147,520 : xnrow,xncol,lgs,lgc,co_s,co_c
extern "C" void kernel_launch(void* const* d_in, const int* in_sizes, int n_in,
                              void* d_out, int out_size, void* d_ws, size_t ws_size,
                              hipStream_t stream)
{
    const float* sent = (const float*)d_in[0];
    const float* comm = (const float*)d_in[1];
    const float* WlW  = (const float*)d_in[2];
    const float* Wlb  = (const float*)d_in[3];
    const float* WcW  = (const float*)d_in[4];
    const float* Wcb  = (const float*)d_in[5];
    const float* WsW  = (const float*)d_in[6];
    const float* Wsb  = (const float*)d_in[7];
    const float* whs  = (const float*)d_in[8];
    const float* whc  = (const float*)d_in[9];
    float* out = (float*)d_out;
    (void)in_sizes; (void)n_in; (void)out_size; (void)ws_size;

    float* ws = (float*)d_ws;
    size_t off = 0;
    auto take = [&](size_t n) { float* p = ws + off; off += n; return p; };
    float* R_big = take(33554432);
    float* Ls    = take(8421376);
    float* Lc    = take(8421376);
    float* R_A   = take(8421376);
    float* R_B   = take(4227072);
    float* xnrow = take(32768);
    float* xncol = take(32768);
    float* lgs   = take(32768);
    float* lgc   = take(32768);
    float* co_s  = take(8224);
    float* co_c  = take(8224);

    // aliases
    float* S1 = R_big;
    float* S2 = R_big + 8388608;
    float* S3 = R_big + 16777216;
    float* Lmat = R_big;
    float* C1  = R_A;
    float* S1n = R_A + 1048576;
    float* C2  = R_A + 2097152;
    float* S2d = R_A + 2162688;
    float* Llin = R_A;
    float* HsA  = R_A;
    float* HcA  = R_A + 4194304;
    float* ytmp = R_B;
    float* slotP = R_B;   // mx_s
    float* slotQ = R_B;   // mx_cT -> Hc (in place)

    float* AsOut = out + 16416;
    float* AcOut = out + 16416 + 32768;

    dim3 blk(256);

    // DFT matrices (live in R_A until both fft2 passes done)
    gendft_kernel<<<4096, 256, 0, stream>>>(C1, S1n, 1024, -1.0f);
    gendft_kernel<<<256, 256, 0, stream>>>(C2, S2d, 256, 1.0f);

    // --- sentence fft2.real = C1*(x*C2) + S1n*(x*S2) -> e2l -> Ls ---
    gemm_tile<false,false,false><<<dim3(4,512,1), blk, 0, stream>>>(sent,256,0, C2,256,0, S1,256,0, nullptr, 32768,256,256);
    gemm_tile<false,false,false><<<dim3(4,512,1), blk, 0, stream>>>(sent,256,0, S2d,256,0, S2,256,0, nullptr, 32768,256,256);
    gemm_tile<false,false,false><<<dim3(4,16,32), blk, 0, stream>>>(C1,1024,0, S1,256,262144, S3,256,262144, nullptr, 1024,256,1024);
    gemm_tile<false,false,true ><<<dim3(4,16,32), blk, 0, stream>>>(S1n,1024,0, S2,256,262144, S3,256,262144, nullptr, 1024,256,1024);
    e2l_kernel<<<32768, 256, 0, stream>>>(S3, Ls);

    // --- comment: p_logmap0 -> fft2.real -> e2l -> Lc ---
    plog_kernel<<<32768, 256, 0, stream>>>(comm, S3);
    gemm_tile<false,false,false><<<dim3(4,512,1), blk, 0, stream>>>(S3,256,0, C2,256,0, S1,256,0, nullptr, 32768,256,256);
    gemm_tile<false,false,false><<<dim3(4,512,1), blk, 0, stream>>>(S3,256,0, S2d,256,0, S2,256,0, nullptr, 32768,256,256);
    gemm_tile<false,false,false><<<dim3(4,16,32), blk, 0, stream>>>(C1,1024,0, S1,256,262144, S3,256,262144, nullptr, 1024,256,1024);
    gemm_tile<false,false,true ><<<dim3(4,16,32), blk, 0, stream>>>(S1n,1024,0, S2,256,262144, S3,256,262144, nullptr, 1024,256,1024);
    e2l_kernel<<<32768, 256, 0, stream>>>(S3, Lc);

    // --- L = lorentz_linear(Lc, Wl) (Llin overwrites DFT mats; both dead) ---
    gemm_tile<false,true,false><<<dim3(5,512,1), blk, 0, stream>>>(Lc,257,0, WlW,257,0, Llin,257,0, Wlb, 32768,257,257);
    lfix_kernel<<<32768, 256, 0, stream>>>(Llin);

    // --- Lmat = lorentz_act(Ls . Llin^T) (overwrites FFT staging; dead) ---
    gemm_tile<false,true,false><<<dim3(16,16,32), blk, 0, stream>>>(Ls,257,263168, Llin,257,263168, Lmat,1024,1048576, nullptr, 1024,1024,257);
    lact_kernel<<<32768, 256, 0, stream>>>(Lmat, xnrow);
    colnorm_kernel<<<dim3(32,4), 256, 0, stream>>>(Lmat, xncol);

    // --- Hs_a / Hc_a (overwrite Llin region; Llin dead after Lmat GEMM) ---
    gemm_tile<false,true,false><<<dim3(3,512,1), blk, 0, stream>>>(Ls,257,0, WsW,257,0, ytmp,129,0, Wsb, 32768,129,257);
    poinc_kernel<<<32768, 128, 0, stream>>>(ytmp, HsA);
    gemm_tile<false,true,false><<<dim3(3,512,1), blk, 0, stream>>>(Lc,257,0, WcW,257,0, ytmp,129,0, Wcb, 32768,129,257);
    poinc_kernel<<<32768, 128, 0, stream>>>(ytmp, HcA);

    // --- Hs path: mx_s = Lmat . Hc_a, rowwise mobius chain -> logits_s ---
    gemm_tile<false,false,false><<<dim3(2,16,32), blk, 0, stream>>>(Lmat,1024,1048576, HcA,128,131072, slotP,128,131072, nullptr, 1024,128,1024);
    rowops_s_kernel<<<32768, 64, 0, stream>>>(HsA, slotP, xnrow, whs, lgs);

    // --- Hc path: mx_c^T[b,j,m] = sum_n Hs_a[b,n,j]*Lmat[b,n,m] (reuses R_B) ---
    gemm_tile<true,false,false><<<dim3(16,2,32), blk, 0, stream>>>(HsA,128,131072, Lmat,1024,1048576, slotQ,1024,131072, nullptr, 128,1024,1024);
    colscale_kernel<<<dim3(32,4), 256, 0, stream>>>(slotQ, xncol);
    rowops_c_kernel<<<4096, 256, 0, stream>>>(HcA, slotQ);
    logitsc_kernel<<<dim3(32,4), 256, 0, stream>>>(slotQ, whc, lgc);

    // --- softmaxes (write directly into d_out) ---
    softmax_kernel<<<32, 256, 0, stream>>>(lgs, AsOut);
    softmax_kernel<<<32, 256, 0, stream>>>(lgc, AcOut);

    // --- centroids + lorentz_concat ---
    centroid_kernel<<<dim3(32,2), 320, 0, stream>>>(Ls, Lc, AsOut, AcOut, co_s, co_c);
    final_kernel<<<32, 256, 0, stream>>>(co_s, co_c, out);
}

// Round 3
// 1006.971 us; speedup vs baseline: 2.8260x; 2.8260x over previous
//
#include <hip/hip_runtime.h>
#include <cstdint>
#include <math.h>

#define NBATCH 32
#define NSQ 1024
#define NCQ 1024
#define DDIM 256
#define DP 257
#define KQ 128
#define KPAD 288   // 257 padded to /32

typedef __attribute__((ext_vector_type(8))) short short8;
typedef __attribute__((ext_vector_type(4))) float floatx4;

// ---------------- device helpers ----------------
__device__ __forceinline__ float bf2f(ushort u) { return __uint_as_float(((uint)u) << 16); }
__device__ __forceinline__ ushort f2bf(float f) {
    uint u = __float_as_uint(f);
    return (ushort)((u + 0x7FFFu + ((u >> 16) & 1u)) >> 16);
}
__device__ __forceinline__ float artanh_clip(float x) {
    x = fminf(fmaxf(x, -1.0f + 1e-5f), 1.0f - 1e-5f);
    return 0.5f * (log1pf(x) - log1pf(-x));
}
__device__ __forceinline__ float gelu_f(float x) {
    return 0.5f * x * (1.0f + erff(x * 0.70710678118654752440f));
}
__device__ __forceinline__ float waveRedSum(float v) {
#pragma unroll
    for (int o = 32; o > 0; o >>= 1) v += __shfl_down(v, o, 64);
    return __shfl(v, 0, 64);
}
__device__ __forceinline__ float blockRedSum(float v, float* buf) {
    int lane = threadIdx.x & 63, wid = threadIdx.x >> 6;
#pragma unroll
    for (int o = 32; o > 0; o >>= 1) v += __shfl_down(v, o, 64);
    __syncthreads();
    if (lane == 0) buf[wid] = v;
    __syncthreads();
    int nw = blockDim.x >> 6;
    float s = buf[0];
    for (int i = 1; i < nw; i++) s += buf[i];
    return s;
}
__device__ __forceinline__ float blockRedMax(float v, float* buf) {
    int lane = threadIdx.x & 63, wid = threadIdx.x >> 6;
#pragma unroll
    for (int o = 32; o > 0; o >>= 1) v = fmaxf(v, __shfl_down(v, o, 64));
    __syncthreads();
    if (lane == 0) buf[wid] = v;
    __syncthreads();
    int nw = blockDim.x >> 6;
    float s = buf[0];
    for (int i = 1; i < nw; i++) s = fmaxf(s, buf[i]);
    return s;
}

// ---------------- bf16 MFMA GEMM ----------------
// C[m,n] = sum_k A[m,k]*B'[k,n] (+bias[n])
// A_NN=false: A is (M x K) row-major.  A_NN=true: A stored (K x M), lda = M-row length.
// B_NN=false: B is (N x K) row-major (bt form, B'[k,n]=B[n,k]). B_NN=true: B stored (K x N), ldb = N-row length.
// M,N multiples of 128; K multiple of 32. bf16 inputs, fp32 MFMA accum.
template <bool A_NN, bool B_NN, bool OUT_BF16, bool BIAS>
__global__ __launch_bounds__(256) void mfma_gemm(
    const short* __restrict__ A, int lda, int64_t sA,
    const short* __restrict__ B, int ldb, int64_t sB,
    void* __restrict__ Cv, int ldc, int64_t sC,
    const float* __restrict__ bias, int M, int N, int K)
{
    __shared__ short As[128][32];
    __shared__ short Bs[128][32];
    A += (int64_t)blockIdx.z * sA;
    B += (int64_t)blockIdx.z * sB;
    const int m0 = blockIdx.y * 128, n0 = blockIdx.x * 128;
    const int t = threadIdx.x;
    const int lane = t & 63, w = t >> 6;
    const int wm = (w & 1) * 64, wn = (w >> 1) * 64;
    floatx4 acc[4][4] = {};
    for (int k0 = 0; k0 < K; k0 += 32) {
        // ---- stage A tile -> As[m][k] ----
        if (!A_NN) {
            int r = t >> 2, c8 = (t & 3) * 8;
            uint4 v1 = *(const uint4*)(A + (int64_t)(m0 + r) * lda + k0 + c8);
            uint4 v2 = *(const uint4*)(A + (int64_t)(m0 + r + 64) * lda + k0 + c8);
            *(uint4*)&As[r][c8] = v1;
            *(uint4*)&As[r + 64][c8] = v2;
        } else {
            int r2 = t >> 4, c8 = (t & 15) * 8;
            int kk = 2 * r2;
            const ushort* a0 = (const ushort*)A + (int64_t)(k0 + kk) * lda + m0 + c8;
            uint4 v0 = *(const uint4*)a0;
            uint4 v1 = *(const uint4*)(a0 + lda);
            const ushort* p0 = (const ushort*)&v0;
            const ushort* p1 = (const ushort*)&v1;
#pragma unroll
            for (int i = 0; i < 8; i++) {
                uint pk = (uint)p0[i] | ((uint)p1[i] << 16);
                *(uint*)&As[c8 + i][kk] = pk;
            }
        }
        // ---- stage B tile -> Bs[n][k] ----
        if (!B_NN) {
            int r = t >> 2, c8 = (t & 3) * 8;
            uint4 v1 = *(const uint4*)(B + (int64_t)(n0 + r) * ldb + k0 + c8);
            uint4 v2 = *(const uint4*)(B + (int64_t)(n0 + r + 64) * ldb + k0 + c8);
            *(uint4*)&Bs[r][c8] = v1;
            *(uint4*)&Bs[r + 64][c8] = v2;
        } else {
            int r2 = t >> 4, c8 = (t & 15) * 8;
            int kk = 2 * r2;
            const ushort* b0 = (const ushort*)B + (int64_t)(k0 + kk) * ldb + n0 + c8;
            uint4 v0 = *(const uint4*)b0;
            uint4 v1 = *(const uint4*)(b0 + ldb);
            const ushort* p0 = (const ushort*)&v0;
            const ushort* p1 = (const ushort*)&v1;
#pragma unroll
            for (int i = 0; i < 8; i++) {
                uint pk = (uint)p0[i] | ((uint)p1[i] << 16);
                *(uint*)&Bs[c8 + i][kk] = pk;
            }
        }
        __syncthreads();
        short8 af[4], bfv[4];
#pragma unroll
        for (int i = 0; i < 4; i++)
            af[i] = *(const short8*)&As[wm + 16 * i + (lane & 15)][8 * (lane >> 4)];
#pragma unroll
        for (int i = 0; i < 4; i++)
            bfv[i] = *(const short8*)&Bs[wn + 16 * i + (lane & 15)][8 * (lane >> 4)];
#pragma unroll
        for (int i = 0; i < 4; i++)
#pragma unroll
            for (int j = 0; j < 4; j++)
                acc[i][j] = __builtin_amdgcn_mfma_f32_16x16x32_bf16(af[i], bfv[j], acc[i][j], 0, 0, 0);
        __syncthreads();
    }
    // ---- epilogue: D row=(lane>>4)*4+reg, col=lane&15 ----
    const int q = lane >> 4, c = lane & 15;
#pragma unroll
    for (int j = 0; j < 4; j++) {
        int col = n0 + wn + 16 * j + c;
        float bv = BIAS ? bias[col] : 0.0f;
#pragma unroll
        for (int i = 0; i < 4; i++) {
            int rowb = m0 + wm + 16 * i + 4 * q;
#pragma unroll
            for (int r = 0; r < 4; r++) {
                float v = acc[i][j][r] + bv;
                int64_t idx = (int64_t)blockIdx.z * sC + (int64_t)(rowb + r) * ldc + col;
                if (OUT_BF16) ((ushort*)Cv)[idx] = f2bf(v);
                else          ((float*)Cv)[idx] = v;
            }
        }
    }
}

// ---------------- DFT matrix generation (bf16) ----------------
__global__ void gen_cs1(ushort* CS1) {
    int idx = blockIdx.x * 256 + threadIdx.x;       // 1024*1024
    int n = idx >> 10, m = idx & 1023;
    int p = (n * m) & 1023;
    float ang = (6.28318530717958647692f / 1024.0f) * (float)p;
    CS1[n * 2048 + m] = f2bf(cosf(ang));
    CS1[n * 2048 + 1024 + m] = f2bf(-sinf(ang));
}
__global__ void gen_c2s2(ushort* C2, ushort* S2) {
    int idx = blockIdx.x * 256 + threadIdx.x;       // 256*256
    int d = idx >> 8, j = idx & 255;
    int p = (d * j) & 255;
    float ang = (6.28318530717958647692f / 256.0f) * (float)p;
    C2[idx] = f2bf(cosf(ang));
    S2[idx] = f2bf(sinf(ang));
}

// weight prep: rows 1.. of W (o x 257) -> bf16 (N x 288), zero-padded
__global__ void wprep_kernel(const float* __restrict__ WlW, const float* __restrict__ WsW,
                             const float* __restrict__ WcW, ushort* Wl, ushort* Ws, ushort* Wc) {
    int r = blockIdx.x, t = threadIdx.x;
    if (t >= KPAD) return;
    const float* src; ushort* dst; int srow;
    if (r < 256)      { src = WlW; dst = Wl + r * KPAD;        srow = r + 1; }
    else if (r < 384) { src = WsW; dst = Ws + (r - 256) * KPAD; srow = r - 256 + 1; }
    else              { src = WcW; dst = Wc + (r - 384) * KPAD; srow = r - 384 + 1; }
    dst[t] = (t < DP) ? f2bf(src[(int64_t)srow * DP + t]) : (ushort)0;
}

// float -> bf16 elementwise
__global__ void cvt_bf_kernel(const float* __restrict__ in, ushort* __restrict__ outp, int n) {
    int i = blockIdx.x * 256 + threadIdx.x;
    if (i * 4 < n) {
        float4 v = *(const float4*)(in + i * 4);
        ushort4 o; o.x = f2bf(v.x); o.y = f2bf(v.y); o.z = f2bf(v.z); o.w = f2bf(v.w);
        *(ushort4*)(outp + i * 4) = o;
    }
}

// p_logmap0 rows of 256, out bf16
__global__ __launch_bounds__(256) void plog_kernel(const float* __restrict__ in, ushort* __restrict__ outp) {
    __shared__ float red[4];
    int64_t row = blockIdx.x; int t = threadIdx.x;
    float v = in[row * 256 + t];
    float s = blockRedSum(v * v, red);
    float yn = sqrtf(fmaxf(s, 1e-15f));
    float fac = artanh_clip(yn) / yn;
    outp[row * 256 + t] = f2bf(fac * v);
}

// euclid_to_lorentz: rows 256 fp32 -> rows 257 fp32 + rows 288 bf16
__global__ __launch_bounds__(256) void e2l_kernel(const float* __restrict__ in,
                                                  float* __restrict__ outp, ushort* __restrict__ obf) {
    __shared__ float red[4];
    int64_t row = blockIdx.x; int t = threadIdx.x;
    float v = in[row * 256 + t];
    float s = blockRedSum(v * v, red);
    float xn = sqrtf(fmaxf(s, 1e-15f)) + 1e-5f;
    float sc = fminf(1.0f, 2.0f / xn);
    float xs = v * sc;
    float s2 = fmaxf(s * sc * sc, 1e-15f);
    float vn = sqrtf(s2);
    float fac = sinhf(vn) / vn;
    float* o = outp + row * DP;
    ushort* ob = obf + row * KPAD;
    float sp = fac * xs;
    if (t == 0) { float tm = coshf(vn); o[0] = tm; ob[0] = f2bf(tm); }
    o[1 + t] = sp;
    ob[1 + t] = f2bf(sp);
    if (t < KPAD - DP) ob[DP + t] = 0;
}

// lorentz_linear space (fp32, 256) -> bf16 row 288 with time at col 0
__global__ __launch_bounds__(256) void lfix2_kernel(const float* __restrict__ sp, ushort* __restrict__ obf) {
    __shared__ float red[4];
    int64_t row = blockIdx.x; int t = threadIdx.x;
    float v = sp[row * 256 + t];
    float s = blockRedSum(v * v, red);
    ushort* ob = obf + row * KPAD;
    if (t == 0) ob[0] = f2bf(sqrtf(s + 1.0f));
    ob[1 + t] = f2bf(v);
    if (t < KPAD - DP) ob[DP + t] = 0;
}

// lorentz_linear(K) space (128) + to_poincare -> fp32 + bf16
__global__ __launch_bounds__(128) void poinc2_kernel(const float* __restrict__ sp,
                                                     float* __restrict__ o32, ushort* __restrict__ obf) {
    __shared__ float red[2];
    int64_t row = blockIdx.x; int t = threadIdx.x;
    float v = sp[row * KQ + t];
    float s = blockRedSum(v * v, red);
    float tim = sqrtf(s + 1.0f);
    float o = v / (tim + 1.0f);
    o32[row * KQ + t] = o;
    obf[row * KQ + t] = f2bf(o);
}

// lorentz_act on bf16 Lmat rows (1024), in place, + xnrow
__global__ __launch_bounds__(256) void lact_kernel(ushort* __restrict__ Lmat, float* __restrict__ xnrow) {
    __shared__ float red[4];
    int64_t row = blockIdx.x; int t = threadIdx.x;
    ushort* r = Lmat + row * (int64_t)NCQ;
    ushort4 u = *(ushort4*)&r[4 * t];
    float v[4] = {bf2f(u.x), bf2f(u.y), bf2f(u.z), bf2f(u.w)};
    float g[4]; float s = 0.f;
#pragma unroll
    for (int i = 0; i < 4; i++) {
        int idx = 4 * t + i;
        if (idx > 0) { g[i] = gelu_f(v[i]); s += g[i] * g[i]; } else g[i] = 0.f;
    }
    s = blockRedSum(s, red);
    if (t == 0) g[0] = sqrtf(1.0f + s);
    ushort4 o; o.x = f2bf(g[0]); o.y = f2bf(g[1]); o.z = f2bf(g[2]); o.w = f2bf(g[3]);
    *(ushort4*)&r[4 * t] = o;
    if (t == 0) xnrow[row] = sqrtf(fmaxf(1.0f + 2.0f * s, 1e-15f));
}

// column norms of bf16 Lmat
__global__ __launch_bounds__(256) void colnorm_kernel(const ushort* __restrict__ Lmat, float* __restrict__ xncol) {
    int b = blockIdx.x; int m = blockIdx.y * 256 + threadIdx.x;
    const ushort* base = Lmat + (int64_t)b * NSQ * NCQ + m;
    float s = 0.f;
    for (int n = 0; n < NSQ; n++) { float v = bf2f(base[n * NCQ]); s += v * v; }
    xncol[b * NCQ + m] = sqrtf(fmaxf(s, 1e-15f));
}

// Hs path rowwise chain -> logits
__global__ __launch_bounds__(64) void rowops_s_kernel(
    const float* __restrict__ Hsa, const float* __restrict__ mxs,
    const float* __restrict__ xnrow, const float* __restrict__ whs,
    float* __restrict__ logits)
{
    int64_t row = blockIdx.x; int t = threadIdx.x;
    const float* p = Hsa + row * KQ;
    const float* q = mxs + row * KQ;
    float p0 = p[t], p1 = p[t + 64], q0 = q[t], q1 = q[t + 64];
    float mxn = sqrtf(fmaxf(waveRedSum(q0 * q0 + q1 * q1), 1e-15f));
    float xn = xnrow[row];
    float fac = tanhf(mxn / xn * artanh_clip(xn)) / mxn;
    float y0 = fac * q0, y1 = fac * q1;
    float xy = waveRedSum(p0 * y0 + p1 * y1);
    float x2 = waveRedSum(p0 * p0 + p1 * p1);
    float y2 = waveRedSum(y0 * y0 + y1 * y1);
    float ca = 1.f + 2.f * xy + y2, cb = 1.f - x2;
    float den = fmaxf(1.f + 2.f * xy + x2 * y2, 1e-15f);
    float h0 = (ca * p0 + cb * y0) / den, h1 = (ca * p1 + cb * y1) / den;
    float hn = sqrtf(fmaxf(waveRedSum(h0 * h0 + h1 * h1), 1e-15f));
    float uf = artanh_clip(hn) / hn;
    float g0 = gelu_f(uf * h0), g1 = gelu_f(uf * h1);
    float gn = sqrtf(fmaxf(waveRedSum(g0 * g0 + g1 * g1), 1e-15f));
    float ef = tanhf(gn) / gn;
    float H0 = ef * g0, H1 = ef * g1;
    float dot = waveRedSum(H0 * whs[t] + H1 * whs[t + 64]);
    float Hn = sqrtf(fmaxf(waveRedSum(H0 * H0 + H1 * H1), 1e-15f));
    float mxn2 = sqrtf(fmaxf(dot * dot, 1e-15f));
    float lg = tanhf(mxn2 / Hn * artanh_clip(Hn)) * dot / mxn2;
    if (t == 0) logits[row] = lg;
}

// mobius_matvec scale on mx_cT columns
__global__ __launch_bounds__(256) void colscale_kernel(float* __restrict__ mxcT, const float* __restrict__ xncol) {
    int b = blockIdx.x; int m = blockIdx.y * 256 + threadIdx.x;
    float* base = mxcT + (int64_t)b * KQ * NCQ + m;
    float s = 0.f;
    for (int j = 0; j < KQ; j++) { float v = base[j * NCQ]; s += v * v; }
    float mxn = sqrtf(fmaxf(s, 1e-15f));
    float xn = xncol[b * NCQ + m];
    float fac = tanhf(mxn / xn * artanh_clip(xn)) / mxn;
    for (int j = 0; j < KQ; j++) base[j * NCQ] *= fac;
}

// Hc path rowwise chain (per (b,k) over NC), in place on y
__global__ __launch_bounds__(256) void rowops_c_kernel(const float* __restrict__ HcA, float* __restrict__ y) {
    __shared__ float red[4];
    int64_t row = blockIdx.x;
    int b = (int)(row >> 7), k = (int)(row & 127);
    const float* xbase = HcA + (int64_t)b * NCQ * KQ + k;
    float* yr = y + row * (int64_t)NCQ;
    int t = threadIdx.x;
    float xv[4], yv[4];
    float xy = 0.f, x2 = 0.f, y2 = 0.f;
#pragma unroll
    for (int i = 0; i < 4; i++) {
        int m = t + 256 * i;
        xv[i] = xbase[(int64_t)m * KQ]; yv[i] = yr[m];
        xy += xv[i] * yv[i]; x2 += xv[i] * xv[i]; y2 += yv[i] * yv[i];
    }
    xy = blockRedSum(xy, red);
    x2 = blockRedSum(x2, red);
    y2 = blockRedSum(y2, red);
    float ca = 1.f + 2.f * xy + y2, cb = 1.f - x2;
    float den = fmaxf(1.f + 2.f * xy + x2 * y2, 1e-15f);
    float h[4]; float hn2 = 0.f;
#pragma unroll
    for (int i = 0; i < 4; i++) { h[i] = (ca * xv[i] + cb * yv[i]) / den; hn2 += h[i] * h[i]; }
    hn2 = blockRedSum(hn2, red);
    float hn = sqrtf(fmaxf(hn2, 1e-15f));
    float uf = artanh_clip(hn) / hn;
    float g[4]; float gn2 = 0.f;
#pragma unroll
    for (int i = 0; i < 4; i++) { g[i] = gelu_f(uf * h[i]); gn2 += g[i] * g[i]; }
    gn2 = blockRedSum(gn2, red);
    float gn = sqrtf(fmaxf(gn2, 1e-15f));
    float ef = tanhf(gn) / gn;
#pragma unroll
    for (int i = 0; i < 4; i++) yr[t + 256 * i] = ef * g[i];
}

// Ac logits
__global__ __launch_bounds__(256) void logitsc_kernel(const float* __restrict__ Hc, const float* __restrict__ whc, float* __restrict__ lgc) {
    int b = blockIdx.x; int m = blockIdx.y * 256 + threadIdx.x;
    const float* base = Hc + (int64_t)b * KQ * NCQ + m;
    float s1 = 0.f, s2 = 0.f;
    for (int j = 0; j < KQ; j++) { float v = base[j * NCQ]; s1 += v * whc[j]; s2 += v * v; }
    float xn = sqrtf(fmaxf(s2, 1e-15f));
    float mxn = sqrtf(fmaxf(s1 * s1, 1e-15f));
    lgc[b * NCQ + m] = tanhf(mxn / xn * artanh_clip(xn)) * s1 / mxn;
}

__global__ __launch_bounds__(256) void softmax_kernel(const float* __restrict__ lg, float* __restrict__ outp) {
    __shared__ float red[4];
    int b = blockIdx.x; int t = threadIdx.x;
    const float* x = lg + b * 1024;
    float v[4]; float m = -1e30f;
#pragma unroll
    for (int i = 0; i < 4; i++) { v[i] = x[t + 256 * i]; m = fmaxf(m, v[i]); }
    m = blockRedMax(m, red);
    float s = 0.f;
#pragma unroll
    for (int i = 0; i < 4; i++) { v[i] = expf(v[i] - m); s += v[i]; }
    s = blockRedSum(s, red);
    float inv = 1.0f / s;
#pragma unroll
    for (int i = 0; i < 4; i++) outp[b * 1024 + t + 256 * i] = v[i] * inv;
}

__global__ __launch_bounds__(320) void centroid_kernel(
    const float* __restrict__ Ls, const float* __restrict__ Lc,
    const float* __restrict__ As, const float* __restrict__ Ac,
    float* __restrict__ co_s, float* __restrict__ co_c)
{
    int b = blockIdx.x;
    bool which = blockIdx.y != 0;
    const float* L = which ? Lc : Ls;
    const float* w = which ? Ac : As;
    float* o = which ? co_c : co_s;
    int t = threadIdx.x;
    if (t >= DP) return;
    const float* Lb = L + (int64_t)b * NSQ * DP + t;
    const float* wb = w + b * NSQ;
    float s = 0.f;
    for (int n = 0; n < NSQ; n++) s += wb[n] * Lb[(int64_t)n * DP];
    o[b * DP + t] = s;
}

__global__ __launch_bounds__(256) void final_kernel(const float* __restrict__ co_s, const float* __restrict__ co_c, float* __restrict__ outp) {
    __shared__ float red[4];
    int b = blockIdx.x, t = threadIdx.x;
    float zmine[2];
    for (int w = 0; w < 2; w++) {
        const float* co = (w ? co_c : co_s) + b * DP;
        float at = co[0];
        float asp = co[1 + t];
        float ssp = blockRedSum(asp * asp, red);
        float li = ssp - at * at;
        float den = sqrtf(fmaxf(fabsf(li), 1e-8f));
        float xt = at / den, xsp = asp / den;
        float s2 = blockRedSum(xsp * xsp, red);
        float nrm = sqrtf(fmaxf(s2, 1e-15f));
        float ac = acoshf(fmaxf(xt, 1.0f + 1e-7f));
        zmine[w] = ac * xsp / nrm;
    }
    float vn2 = blockRedSum(zmine[0] * zmine[0] + zmine[1] * zmine[1], red);
    float vn = sqrtf(fmaxf(vn2, 1e-15f));
    float sc = sinhf(vn) / vn;
    if (t == 0) outp[b * 513] = coshf(vn);
    outp[b * 513 + 1 + t] = sc * zmine[0];
    outp[b * 513 + 1 + 256 + t] = sc * zmine[1];
}

// ---------------- host launcher ----------------
extern "C" void kernel_launch(void* const* d_in, const int* in_sizes, int n_in,
                              void* d_out, int out_size, void* d_ws, size_t ws_size,
                              hipStream_t stream)
{
    const float* sent = (const float*)d_in[0];
    const float* comm = (const float*)d_in[1];
    const float* WlW  = (const float*)d_in[2];
    const float* Wlb  = (const float*)d_in[3];
    const float* WcW  = (const float*)d_in[4];
    const float* Wcb  = (const float*)d_in[5];
    const float* WsW  = (const float*)d_in[6];
    const float* Wsb  = (const float*)d_in[7];
    const float* whs  = (const float*)d_in[8];
    const float* whc  = (const float*)d_in[9];
    float* out = (float*)d_out;
    (void)in_sizes; (void)n_in; (void)out_size; (void)ws_size;

    float* ws = (float*)d_ws;
    size_t off = 0;
    auto take = [&](size_t n) { float* p = ws + off; off += n; return p; };
    float*  Ls    = take(8421376);
    float*  Lc    = take(8421376);
    float*  xnrow = take(32768);
    float*  xncol = take(32768);
    float*  lgs   = take(32768);
    float*  lgc   = take(32768);
    float*  co_s  = take(8224);
    float*  co_c  = take(8224);
    ushort* Ls_bf = (ushort*)take(4718592);
    ushort* Lc_bf = (ushort*)take(4718592);
    ushort* Wl_bf = (ushort*)take(36864);
    ushort* Ws_bf = (ushort*)take(18432);
    ushort* Wc_bf = (ushort*)take(18432);
    float*  F     = take(33554432);   // total 60,055,616 fl = 240.2 MiB

    // Phase overlays in F (float offsets)
    ushort* Lmat_bf = (ushort*)F;                 // [P3-P5] 16,777,216 fl
    ushort* Llin_bf = (ushort*)(F + 16777216);    // [P2-P3] 4,718,592 fl
    float*  Llin_sp = F + 21495808;               // [P2]    8,388,608 fl
    float*  ytmp    = F + 16777216;               // [P4]    4,194,304 fl
    float*  HsA     = F + 20971520;               // [P4-P5] 4,194,304 fl
    float*  HcA     = F + 25165824;               // [P4-P5] 4,194,304 fl
    ushort* HsA_bf  = (ushort*)(F + 29360128);    // [P4-P5] 2,097,152 fl
    ushort* HcA_bf  = (ushort*)(F + 31457280);    // [P4-P5] 2,097,152 fl
    float*  mx      = F + 16777216;               // [P5]    4,194,304 fl (= ytmp slot)
    ushort* Xin_bf  = (ushort*)F;                 // [P1] 4,194,304 fl
    ushort* Z_bf    = (ushort*)(F + 4194304);     // [P1] 8,388,608 fl
    ushort* CS1     = (ushort*)(F + 12582912);    // [P1] 1,048,576 fl
    ushort* C2_bf   = (ushort*)(F + 13631488);    // [P1] 32,768 fl
    ushort* S2_bf   = (ushort*)(F + 13664256);    // [P1] 32,768 fl
    float*  Yst     = F + 13697024;               // [P1] 8,388,608 fl

    float* AsOut = out + 16416;
    float* AcOut = out + 16416 + 32768;

    dim3 blk(256);

    // constants
    gen_cs1<<<4096, 256, 0, stream>>>(CS1);
    gen_c2s2<<<256, 256, 0, stream>>>(C2_bf, S2_bf);
    wprep_kernel<<<512, 320, 0, stream>>>(WlW, WsW, WcW, Wl_bf, Ws_bf, Wc_bf);

    // ---- sentence: fft2.real -> e2l -> Ls ----
    cvt_bf_kernel<<<8192, 256, 0, stream>>>(sent, Xin_bf, 8388608);
    mfma_gemm<false,false,true,false><<<dim3(2,8,32), blk, 0, stream>>>(
        (const short*)Xin_bf,256,262144, (const short*)C2_bf,256,0, Z_bf,256,524288, nullptr, 1024,256,256);
    mfma_gemm<false,false,true,false><<<dim3(2,8,32), blk, 0, stream>>>(
        (const short*)Xin_bf,256,262144, (const short*)S2_bf,256,0, Z_bf+262144,256,524288, nullptr, 1024,256,256);
    mfma_gemm<false,true,false,false><<<dim3(2,8,32), blk, 0, stream>>>(
        (const short*)CS1,2048,0, (const short*)Z_bf,256,524288, Yst,256,262144, nullptr, 1024,256,2048);
    e2l_kernel<<<32768, 256, 0, stream>>>(Yst, Ls, Ls_bf);

    // ---- comment: p_logmap0 -> fft2.real -> e2l -> Lc ----
    plog_kernel<<<32768, 256, 0, stream>>>(comm, Xin_bf);
    mfma_gemm<false,false,true,false><<<dim3(2,8,32), blk, 0, stream>>>(
        (const short*)Xin_bf,256,262144, (const short*)C2_bf,256,0, Z_bf,256,524288, nullptr, 1024,256,256);
    mfma_gemm<false,false,true,false><<<dim3(2,8,32), blk, 0, stream>>>(
        (const short*)Xin_bf,256,262144, (const short*)S2_bf,256,0, Z_bf+262144,256,524288, nullptr, 1024,256,256);
    mfma_gemm<false,true,false,false><<<dim3(2,8,32), blk, 0, stream>>>(
        (const short*)CS1,2048,0, (const short*)Z_bf,256,524288, Yst,256,262144, nullptr, 1024,256,2048);
    e2l_kernel<<<32768, 256, 0, stream>>>(Yst, Lc, Lc_bf);

    // ---- L = lorentz_linear(Lc, Wl): space cols only ----
    mfma_gemm<false,false,false,true><<<dim3(2,256,1), blk, 0, stream>>>(
        (const short*)Lc_bf,KPAD,0, (const short*)Wl_bf,KPAD,0, Llin_sp,256,0, Wlb+1, 32768,256,KPAD);
    lfix2_kernel<<<32768, 256, 0, stream>>>(Llin_sp, Llin_bf);

    // ---- Lmat = lorentz_act(einsum(Ls, Llin)) in bf16 ----
    mfma_gemm<false,false,true,false><<<dim3(8,8,32), blk, 0, stream>>>(
        (const short*)Ls_bf,KPAD,294912, (const short*)Llin_bf,KPAD,294912, Lmat_bf,1024,1048576, nullptr, 1024,1024,KPAD);
    lact_kernel<<<32768, 256, 0, stream>>>(Lmat_bf, xnrow);
    colnorm_kernel<<<dim3(32,4), 256, 0, stream>>>(Lmat_bf, xncol);

    // ---- Hs_a / Hc_a ----
    mfma_gemm<false,false,false,true><<<dim3(1,256,1), blk, 0, stream>>>(
        (const short*)Ls_bf,KPAD,0, (const short*)Ws_bf,KPAD,0, ytmp,128,0, Wsb+1, 32768,128,KPAD);
    poinc2_kernel<<<32768, 128, 0, stream>>>(ytmp, HsA, HsA_bf);
    mfma_gemm<false,false,false,true><<<dim3(1,256,1), blk, 0, stream>>>(
        (const short*)Lc_bf,KPAD,0, (const short*)Wc_bf,KPAD,0, ytmp,128,0, Wcb+1, 32768,128,KPAD);
    poinc2_kernel<<<32768, 128, 0, stream>>>(ytmp, HcA, HcA_bf);

    // ---- Hs path: mx_s = Lmat . Hc_a ----
    mfma_gemm<false,true,false,false><<<dim3(1,8,32), blk, 0, stream>>>(
        (const short*)Lmat_bf,1024,1048576, (const short*)HcA_bf,128,131072, mx,128,131072, nullptr, 1024,128,1024);
    rowops_s_kernel<<<32768, 64, 0, stream>>>(HsA, mx, xnrow, whs, lgs);

    // ---- Hc path: mx_cT = Hs_a^T . Lmat ----
    mfma_gemm<true,true,false,false><<<dim3(8,1,32), blk, 0, stream>>>(
        (const short*)HsA_bf,128,131072, (const short*)Lmat_bf,1024,1048576, mx,1024,131072, nullptr, 128,1024,1024);
    colscale_kernel<<<dim3(32,4), 256, 0, stream>>>(mx, xncol);
    rowops_c_kernel<<<4096, 256, 0, stream>>>(HcA, mx);
    logitsc_kernel<<<dim3(32,4), 256, 0, stream>>>(mx, whc, lgc);

    // ---- softmaxes / centroids / concat ----
    softmax_kernel<<<32, 256, 0, stream>>>(lgs, AsOut);
    softmax_kernel<<<32, 256, 0, stream>>>(lgc, AcOut);
    centroid_kernel<<<dim3(32,2), 320, 0, stream>>>(Ls, Lc, AsOut, AcOut, co_s, co_c);
    final_kernel<<<32, 256, 0, stream>>>(co_s, co_c, out);
}

// Round 4
// 820.040 us; speedup vs baseline: 3.4702x; 1.2280x over previous
//
#include <hip/hip_runtime.h>
#include <cstdint>
#include <math.h>

#define NBATCH 32
#define NSQ 1024
#define NCQ 1024
#define DDIM 256
#define DP 257
#define KQ 128
#define KPAD 288   // 257 padded to /32

typedef __attribute__((ext_vector_type(8))) short short8;
typedef __attribute__((ext_vector_type(4))) float floatx4;

// ---------------- device helpers ----------------
__device__ __forceinline__ float bf2f(ushort u) { return __uint_as_float(((uint)u) << 16); }
__device__ __forceinline__ ushort f2bf(float f) {
    uint u = __float_as_uint(f);
    return (ushort)((u + 0x7FFFu + ((u >> 16) & 1u)) >> 16);
}
__device__ __forceinline__ float artanh_clip(float x) {
    x = fminf(fmaxf(x, -1.0f + 1e-5f), 1.0f - 1e-5f);
    return 0.5f * (log1pf(x) - log1pf(-x));
}
__device__ __forceinline__ float gelu_f(float x) {
    return 0.5f * x * (1.0f + erff(x * 0.70710678118654752440f));
}
__device__ __forceinline__ float waveRedSum(float v) {
#pragma unroll
    for (int o = 32; o > 0; o >>= 1) v += __shfl_down(v, o, 64);
    return __shfl(v, 0, 64);
}
__device__ __forceinline__ float blockRedSum(float v, float* buf) {
    int lane = threadIdx.x & 63, wid = threadIdx.x >> 6;
#pragma unroll
    for (int o = 32; o > 0; o >>= 1) v += __shfl_down(v, o, 64);
    __syncthreads();
    if (lane == 0) buf[wid] = v;
    __syncthreads();
    int nw = blockDim.x >> 6;
    float s = buf[0];
    for (int i = 1; i < nw; i++) s += buf[i];
    return s;
}
__device__ __forceinline__ float blockRedMax(float v, float* buf) {
    int lane = threadIdx.x & 63, wid = threadIdx.x >> 6;
#pragma unroll
    for (int o = 32; o > 0; o >>= 1) v = fmaxf(v, __shfl_down(v, o, 64));
    __syncthreads();
    if (lane == 0) buf[wid] = v;
    __syncthreads();
    int nw = blockDim.x >> 6;
    float s = buf[0];
    for (int i = 1; i < nw; i++) s = fmaxf(s, buf[i]);
    return s;
}

// ---------------- bf16 MFMA GEMM ----------------
// C[m,n] = sum_k A[m,k]*B'[k,n] (+bias[n])
// A_NN=false: A is (M x K) row-major.  A_NN=true: A stored (K x M).
// B_NN=false: B is (N x K) row-major (bt form). B_NN=true: B stored (K x N).
// M,N multiples of 128; K multiple of 32. bf16 inputs, fp32 MFMA accum.
template <bool A_NN, bool B_NN, bool OUT_BF16, bool BIAS>
__global__ __launch_bounds__(256) void mfma_gemm(
    const short* __restrict__ A, int lda, int64_t sA,
    const short* __restrict__ B, int ldb, int64_t sB,
    void* __restrict__ Cv, int ldc, int64_t sC,
    const float* __restrict__ bias, int M, int N, int K)
{
    __shared__ short As[128][32];
    __shared__ short Bs[128][32];
    A += (int64_t)blockIdx.z * sA;
    B += (int64_t)blockIdx.z * sB;
    const int m0 = blockIdx.y * 128, n0 = blockIdx.x * 128;
    const int t = threadIdx.x;
    const int lane = t & 63, w = t >> 6;
    const int wm = (w & 1) * 64, wn = (w >> 1) * 64;
    floatx4 acc[4][4] = {};
    for (int k0 = 0; k0 < K; k0 += 32) {
        // ---- stage A tile -> As[m][k] ----
        if (!A_NN) {
            int r = t >> 2, c8 = (t & 3) * 8;
            uint4 v1 = *(const uint4*)(A + (int64_t)(m0 + r) * lda + k0 + c8);
            uint4 v2 = *(const uint4*)(A + (int64_t)(m0 + r + 64) * lda + k0 + c8);
            *(uint4*)&As[r][c8] = v1;
            *(uint4*)&As[r + 64][c8] = v2;
        } else {
            int r2 = t >> 4, c8 = (t & 15) * 8;
            int kk = 2 * r2;
            const ushort* a0 = (const ushort*)A + (int64_t)(k0 + kk) * lda + m0 + c8;
            uint4 v0 = *(const uint4*)a0;
            uint4 v1 = *(const uint4*)(a0 + lda);
            const ushort* p0 = (const ushort*)&v0;
            const ushort* p1 = (const ushort*)&v1;
#pragma unroll
            for (int i = 0; i < 8; i++) {
                uint pk = (uint)p0[i] | ((uint)p1[i] << 16);
                *(uint*)&As[c8 + i][kk] = pk;
            }
        }
        // ---- stage B tile -> Bs[n][k] ----
        if (!B_NN) {
            int r = t >> 2, c8 = (t & 3) * 8;
            uint4 v1 = *(const uint4*)(B + (int64_t)(n0 + r) * ldb + k0 + c8);
            uint4 v2 = *(const uint4*)(B + (int64_t)(n0 + r + 64) * ldb + k0 + c8);
            *(uint4*)&Bs[r][c8] = v1;
            *(uint4*)&Bs[r + 64][c8] = v2;
        } else {
            int r2 = t >> 4, c8 = (t & 15) * 8;
            int kk = 2 * r2;
            const ushort* b0 = (const ushort*)B + (int64_t)(k0 + kk) * ldb + n0 + c8;
            uint4 v0 = *(const uint4*)b0;
            uint4 v1 = *(const uint4*)(b0 + ldb);
            const ushort* p0 = (const ushort*)&v0;
            const ushort* p1 = (const ushort*)&v1;
#pragma unroll
            for (int i = 0; i < 8; i++) {
                uint pk = (uint)p0[i] | ((uint)p1[i] << 16);
                *(uint*)&Bs[c8 + i][kk] = pk;
            }
        }
        __syncthreads();
        short8 af[4], bfv[4];
#pragma unroll
        for (int i = 0; i < 4; i++)
            af[i] = *(const short8*)&As[wm + 16 * i + (lane & 15)][8 * (lane >> 4)];
#pragma unroll
        for (int i = 0; i < 4; i++)
            bfv[i] = *(const short8*)&Bs[wn + 16 * i + (lane & 15)][8 * (lane >> 4)];
#pragma unroll
        for (int i = 0; i < 4; i++)
#pragma unroll
            for (int j = 0; j < 4; j++)
                acc[i][j] = __builtin_amdgcn_mfma_f32_16x16x32_bf16(af[i], bfv[j], acc[i][j], 0, 0, 0);
        __syncthreads();
    }
    // ---- epilogue: D row=(lane>>4)*4+reg, col=lane&15 ----
    const int q = lane >> 4, c = lane & 15;
#pragma unroll
    for (int j = 0; j < 4; j++) {
        int col = n0 + wn + 16 * j + c;
        float bv = BIAS ? bias[col] : 0.0f;
#pragma unroll
        for (int i = 0; i < 4; i++) {
            int rowb = m0 + wm + 16 * i + 4 * q;
#pragma unroll
            for (int r = 0; r < 4; r++) {
                float v = acc[i][j][r] + bv;
                int64_t idx = (int64_t)blockIdx.z * sC + (int64_t)(rowb + r) * ldc + col;
                if (OUT_BF16) ((ushort*)Cv)[idx] = f2bf(v);
                else          ((float*)Cv)[idx] = v;
            }
        }
    }
}

// ---------------- DFT matrix generation (bf16) ----------------
__global__ void gen_cs1(ushort* CS1) {
    int idx = blockIdx.x * 256 + threadIdx.x;       // 1024*1024
    int n = idx >> 10, m = idx & 1023;
    int p = (n * m) & 1023;
    float ang = (6.28318530717958647692f / 1024.0f) * (float)p;
    CS1[n * 2048 + m] = f2bf(cosf(ang));
    CS1[n * 2048 + 1024 + m] = f2bf(-sinf(ang));
}
__global__ void gen_c2s2(ushort* C2, ushort* S2) {
    int idx = blockIdx.x * 256 + threadIdx.x;       // 256*256
    int d = idx >> 8, j = idx & 255;
    int p = (d * j) & 255;
    float ang = (6.28318530717958647692f / 256.0f) * (float)p;
    C2[idx] = f2bf(cosf(ang));
    S2[idx] = f2bf(sinf(ang));
}

// weight prep: rows 1.. of W (o x 257) -> bf16 (N x 288), zero-padded
__global__ void wprep_kernel(const float* __restrict__ WlW, const float* __restrict__ WsW,
                             const float* __restrict__ WcW, ushort* Wl, ushort* Ws, ushort* Wc) {
    int r = blockIdx.x, t = threadIdx.x;
    if (t >= KPAD) return;
    const float* src; ushort* dst; int srow;
    if (r < 256)      { src = WlW; dst = Wl + r * KPAD;        srow = r + 1; }
    else if (r < 384) { src = WsW; dst = Ws + (r - 256) * KPAD; srow = r - 256 + 1; }
    else              { src = WcW; dst = Wc + (r - 384) * KPAD; srow = r - 384 + 1; }
    dst[t] = (t < DP) ? f2bf(src[(int64_t)srow * DP + t]) : (ushort)0;
}

// float -> bf16 elementwise
__global__ void cvt_bf_kernel(const float* __restrict__ in, ushort* __restrict__ outp, int n) {
    int i = blockIdx.x * 256 + threadIdx.x;
    if (i * 4 < n) {
        float4 v = *(const float4*)(in + i * 4);
        ushort4 o; o.x = f2bf(v.x); o.y = f2bf(v.y); o.z = f2bf(v.z); o.w = f2bf(v.w);
        *(ushort4*)(outp + i * 4) = o;
    }
}

// p_logmap0 rows of 256, out bf16
__global__ __launch_bounds__(256) void plog_kernel(const float* __restrict__ in, ushort* __restrict__ outp) {
    __shared__ float red[4];
    int64_t row = blockIdx.x; int t = threadIdx.x;
    float v = in[row * 256 + t];
    float s = blockRedSum(v * v, red);
    float yn = sqrtf(fmaxf(s, 1e-15f));
    float fac = artanh_clip(yn) / yn;
    outp[row * 256 + t] = f2bf(fac * v);
}

// euclid_to_lorentz: rows 256 fp32 -> rows 257 fp32 + rows 288 bf16
__global__ __launch_bounds__(256) void e2l_kernel(const float* __restrict__ in,
                                                  float* __restrict__ outp, ushort* __restrict__ obf) {
    __shared__ float red[4];
    int64_t row = blockIdx.x; int t = threadIdx.x;
    float v = in[row * 256 + t];
    float s = blockRedSum(v * v, red);
    float xn = sqrtf(fmaxf(s, 1e-15f)) + 1e-5f;
    float sc = fminf(1.0f, 2.0f / xn);
    float xs = v * sc;
    float s2 = fmaxf(s * sc * sc, 1e-15f);
    float vn = sqrtf(s2);
    float fac = sinhf(vn) / vn;
    float* o = outp + row * DP;
    ushort* ob = obf + row * KPAD;
    float sp = fac * xs;
    if (t == 0) { float tm = coshf(vn); o[0] = tm; ob[0] = f2bf(tm); }
    o[1 + t] = sp;
    ob[1 + t] = f2bf(sp);
    if (t < KPAD - DP) ob[DP + t] = 0;
}

// lorentz_linear space (fp32, 256) -> bf16 row 288 with time at col 0
__global__ __launch_bounds__(256) void lfix2_kernel(const float* __restrict__ sp, ushort* __restrict__ obf) {
    __shared__ float red[4];
    int64_t row = blockIdx.x; int t = threadIdx.x;
    float v = sp[row * 256 + t];
    float s = blockRedSum(v * v, red);
    ushort* ob = obf + row * KPAD;
    if (t == 0) ob[0] = f2bf(sqrtf(s + 1.0f));
    ob[1 + t] = f2bf(v);
    if (t < KPAD - DP) ob[DP + t] = 0;
}

// lorentz_linear(K) space (128) + to_poincare -> fp32 + bf16
__global__ __launch_bounds__(128) void poinc2_kernel(const float* __restrict__ sp,
                                                     float* __restrict__ o32, ushort* __restrict__ obf) {
    __shared__ float red[2];
    int64_t row = blockIdx.x; int t = threadIdx.x;
    float v = sp[row * KQ + t];
    float s = blockRedSum(v * v, red);
    float tim = sqrtf(s + 1.0f);
    float o = v / (tim + 1.0f);
    o32[row * KQ + t] = o;
    obf[row * KQ + t] = f2bf(o);
}

// lorentz_act on bf16 Lmat rows (1024), in place, + xnrow
__global__ __launch_bounds__(256) void lact_kernel(ushort* __restrict__ Lmat, float* __restrict__ xnrow) {
    __shared__ float red[4];
    int64_t row = blockIdx.x; int t = threadIdx.x;
    ushort* r = Lmat + row * (int64_t)NCQ;
    ushort4 u = *(ushort4*)&r[4 * t];
    float v[4] = {bf2f(u.x), bf2f(u.y), bf2f(u.z), bf2f(u.w)};
    float g[4]; float s = 0.f;
#pragma unroll
    for (int i = 0; i < 4; i++) {
        int idx = 4 * t + i;
        if (idx > 0) { g[i] = gelu_f(v[i]); s += g[i] * g[i]; } else g[i] = 0.f;
    }
    s = blockRedSum(s, red);
    if (t == 0) g[0] = sqrtf(1.0f + s);
    ushort4 o; o.x = f2bf(g[0]); o.y = f2bf(g[1]); o.z = f2bf(g[2]); o.w = f2bf(g[3]);
    *(ushort4*)&r[4 * t] = o;
    if (t == 0) xnrow[row] = sqrtf(fmaxf(1.0f + 2.0f * s, 1e-15f));
}

// column-norm stage A: per (b, row-chunk of 128) accumulate sq-sums for 4 cols/thread
__global__ __launch_bounds__(256) void colnormA_kernel(const ushort* __restrict__ Lmat, float* __restrict__ part) {
    int b = blockIdx.x, chunk = blockIdx.y, t = threadIdx.x;
    const ushort* base = Lmat + (int64_t)b * NSQ * NCQ + (int64_t)chunk * 128 * NCQ + 4 * t;
    float s0 = 0.f, s1 = 0.f, s2 = 0.f, s3 = 0.f;
    for (int n = 0; n < 128; n++) {
        ushort4 u = *(const ushort4*)(base + (int64_t)n * NCQ);
        float a = bf2f(u.x), bb = bf2f(u.y), c = bf2f(u.z), d = bf2f(u.w);
        s0 += a * a; s1 += bb * bb; s2 += c * c; s3 += d * d;
    }
    float4 o = {s0, s1, s2, s3};
    *(float4*)(part + ((int64_t)(b * 8 + chunk)) * 4096 + 4 * t) = o;
}
__global__ __launch_bounds__(256) void colnormB_kernel(const float* __restrict__ part, float* __restrict__ xncol) {
    int b = blockIdx.x; int m = blockIdx.y * 256 + threadIdx.x;
    const float* p = part + (int64_t)b * 8 * 4096 + m;
    float s = 0.f;
#pragma unroll
    for (int c = 0; c < 8; c++) s += p[c * 4096];
    xncol[b * NCQ + m] = sqrtf(fmaxf(s, 1e-15f));
}

// Hs path rowwise chain -> logits
__global__ __launch_bounds__(64) void rowops_s_kernel(
    const float* __restrict__ Hsa, const float* __restrict__ mxs,
    const float* __restrict__ xnrow, const float* __restrict__ whs,
    float* __restrict__ logits)
{
    int64_t row = blockIdx.x; int t = threadIdx.x;
    const float* p = Hsa + row * KQ;
    const float* q = mxs + row * KQ;
    float p0 = p[t], p1 = p[t + 64], q0 = q[t], q1 = q[t + 64];
    float mxn = sqrtf(fmaxf(waveRedSum(q0 * q0 + q1 * q1), 1e-15f));
    float xn = xnrow[row];
    float fac = tanhf(mxn / xn * artanh_clip(xn)) / mxn;
    float y0 = fac * q0, y1 = fac * q1;
    float xy = waveRedSum(p0 * y0 + p1 * y1);
    float x2 = waveRedSum(p0 * p0 + p1 * p1);
    float y2 = waveRedSum(y0 * y0 + y1 * y1);
    float ca = 1.f + 2.f * xy + y2, cb = 1.f - x2;
    float den = fmaxf(1.f + 2.f * xy + x2 * y2, 1e-15f);
    float h0 = (ca * p0 + cb * y0) / den, h1 = (ca * p1 + cb * y1) / den;
    float hn = sqrtf(fmaxf(waveRedSum(h0 * h0 + h1 * h1), 1e-15f));
    float uf = artanh_clip(hn) / hn;
    float g0 = gelu_f(uf * h0), g1 = gelu_f(uf * h1);
    float gn = sqrtf(fmaxf(waveRedSum(g0 * g0 + g1 * g1), 1e-15f));
    float ef = tanhf(gn) / gn;
    float H0 = ef * g0, H1 = ef * g1;
    float dot = waveRedSum(H0 * whs[t] + H1 * whs[t + 64]);
    float Hn = sqrtf(fmaxf(waveRedSum(H0 * H0 + H1 * H1), 1e-15f));
    float mxn2 = sqrtf(fmaxf(dot * dot, 1e-15f));
    float lg = tanhf(mxn2 / Hn * artanh_clip(Hn)) * dot / mxn2;
    if (t == 0) logits[row] = lg;
}

// mobius_matvec scale on mx_cT columns
__global__ __launch_bounds__(256) void colscale_kernel(float* __restrict__ mxcT, const float* __restrict__ xncol) {
    int b = blockIdx.x; int m = blockIdx.y * 256 + threadIdx.x;
    float* base = mxcT + (int64_t)b * KQ * NCQ + m;
    float s = 0.f;
    for (int j = 0; j < KQ; j++) { float v = base[j * NCQ]; s += v * v; }
    float mxn = sqrtf(fmaxf(s, 1e-15f));
    float xn = xncol[b * NCQ + m];
    float fac = tanhf(mxn / xn * artanh_clip(xn)) / mxn;
    for (int j = 0; j < KQ; j++) base[j * NCQ] *= fac;
}

// Hc path rowwise chain (per (b,k) over NC), in place on y
__global__ __launch_bounds__(256) void rowops_c_kernel(const float* __restrict__ HcA, float* __restrict__ y) {
    __shared__ float red[4];
    int64_t row = blockIdx.x;
    int b = (int)(row >> 7), k = (int)(row & 127);
    const float* xbase = HcA + (int64_t)b * NCQ * KQ + k;
    float* yr = y + row * (int64_t)NCQ;
    int t = threadIdx.x;
    float xv[4], yv[4];
    float xy = 0.f, x2 = 0.f, y2 = 0.f;
#pragma unroll
    for (int i = 0; i < 4; i++) {
        int m = t + 256 * i;
        xv[i] = xbase[(int64_t)m * KQ]; yv[i] = yr[m];
        xy += xv[i] * yv[i]; x2 += xv[i] * xv[i]; y2 += yv[i] * yv[i];
    }
    xy = blockRedSum(xy, red);
    x2 = blockRedSum(x2, red);
    y2 = blockRedSum(y2, red);
    float ca = 1.f + 2.f * xy + y2, cb = 1.f - x2;
    float den = fmaxf(1.f + 2.f * xy + x2 * y2, 1e-15f);
    float h[4]; float hn2 = 0.f;
#pragma unroll
    for (int i = 0; i < 4; i++) { h[i] = (ca * xv[i] + cb * yv[i]) / den; hn2 += h[i] * h[i]; }
    hn2 = blockRedSum(hn2, red);
    float hn = sqrtf(fmaxf(hn2, 1e-15f));
    float uf = artanh_clip(hn) / hn;
    float g[4]; float gn2 = 0.f;
#pragma unroll
    for (int i = 0; i < 4; i++) { g[i] = gelu_f(uf * h[i]); gn2 += g[i] * g[i]; }
    gn2 = blockRedSum(gn2, red);
    float gn = sqrtf(fmaxf(gn2, 1e-15f));
    float ef = tanhf(gn) / gn;
#pragma unroll
    for (int i = 0; i < 4; i++) yr[t + 256 * i] = ef * g[i];
}

// Ac logits
__global__ __launch_bounds__(256) void logitsc_kernel(const float* __restrict__ Hc, const float* __restrict__ whc, float* __restrict__ lgc) {
    int b = blockIdx.x; int m = blockIdx.y * 256 + threadIdx.x;
    const float* base = Hc + (int64_t)b * KQ * NCQ + m;
    float s1 = 0.f, s2 = 0.f;
    for (int j = 0; j < KQ; j++) { float v = base[j * NCQ]; s1 += v * whc[j]; s2 += v * v; }
    float xn = sqrtf(fmaxf(s2, 1e-15f));
    float mxn = sqrtf(fmaxf(s1 * s1, 1e-15f));
    lgc[b * NCQ + m] = tanhf(mxn / xn * artanh_clip(xn)) * s1 / mxn;
}

__global__ __launch_bounds__(256) void softmax_kernel(const float* __restrict__ lg, float* __restrict__ outp) {
    __shared__ float red[4];
    int b = blockIdx.x; int t = threadIdx.x;
    const float* x = lg + b * 1024;
    float v[4]; float m = -1e30f;
#pragma unroll
    for (int i = 0; i < 4; i++) { v[i] = x[t + 256 * i]; m = fmaxf(m, v[i]); }
    m = blockRedMax(m, red);
    float s = 0.f;
#pragma unroll
    for (int i = 0; i < 4; i++) { v[i] = expf(v[i] - m); s += v[i]; }
    s = blockRedSum(s, red);
    float inv = 1.0f / s;
#pragma unroll
    for (int i = 0; i < 4; i++) outp[b * 1024 + t + 256 * i] = v[i] * inv;
}

// centroid stage A: partial sums over 128-row chunks (deterministic 2-stage)
__global__ __launch_bounds__(320) void centroidA_kernel(
    const float* __restrict__ Ls, const float* __restrict__ Lc,
    const float* __restrict__ As, const float* __restrict__ Ac,
    float* __restrict__ part)
{
    int b = blockIdx.x;
    int which = blockIdx.y;
    int chunk = blockIdx.z;
    const float* L = which ? Lc : Ls;
    const float* w = which ? Ac : As;
    int t = threadIdx.x;
    if (t >= DP) return;
    const float* Lb = L + (int64_t)b * NSQ * DP + (int64_t)chunk * 128 * DP + t;
    const float* wb = w + b * NSQ + chunk * 128;
    float s = 0.f;
    for (int n = 0; n < 128; n++) s += wb[n] * Lb[(int64_t)n * DP];
    part[((int64_t)((b * 2 + which) * 8 + chunk)) * 264 + t] = s;
}
__global__ __launch_bounds__(320) void centroidB_kernel(
    const float* __restrict__ part, float* __restrict__ co_s, float* __restrict__ co_c)
{
    int b = blockIdx.x;
    int which = blockIdx.y;
    int t = threadIdx.x;
    if (t >= DP) return;
    const float* p = part + (int64_t)(b * 2 + which) * 8 * 264 + t;
    float s = 0.f;
#pragma unroll
    for (int c = 0; c < 8; c++) s += p[c * 264];
    (which ? co_c : co_s)[b * DP + t] = s;
}

__global__ __launch_bounds__(256) void final_kernel(const float* __restrict__ co_s, const float* __restrict__ co_c, float* __restrict__ outp) {
    __shared__ float red[4];
    int b = blockIdx.x, t = threadIdx.x;
    float zmine[2];
    for (int w = 0; w < 2; w++) {
        const float* co = (w ? co_c : co_s) + b * DP;
        float at = co[0];
        float asp = co[1 + t];
        float ssp = blockRedSum(asp * asp, red);
        float li = ssp - at * at;
        float den = sqrtf(fmaxf(fabsf(li), 1e-8f));
        float xt = at / den, xsp = asp / den;
        float s2 = blockRedSum(xsp * xsp, red);
        float nrm = sqrtf(fmaxf(s2, 1e-15f));
        float ac = acoshf(fmaxf(xt, 1.0f + 1e-7f));
        zmine[w] = ac * xsp / nrm;
    }
    float vn2 = blockRedSum(zmine[0] * zmine[0] + zmine[1] * zmine[1], red);
    float vn = sqrtf(fmaxf(vn2, 1e-15f));
    float sc = sinhf(vn) / vn;
    if (t == 0) outp[b * 513] = coshf(vn);
    outp[b * 513 + 1 + t] = sc * zmine[0];
    outp[b * 513 + 1 + 256 + t] = sc * zmine[1];
}

// ---------------- host launcher ----------------
extern "C" void kernel_launch(void* const* d_in, const int* in_sizes, int n_in,
                              void* d_out, int out_size, void* d_ws, size_t ws_size,
                              hipStream_t stream)
{
    const float* sent = (const float*)d_in[0];
    const float* comm = (const float*)d_in[1];
    const float* WlW  = (const float*)d_in[2];
    const float* Wlb  = (const float*)d_in[3];
    const float* WcW  = (const float*)d_in[4];
    const float* Wcb  = (const float*)d_in[5];
    const float* WsW  = (const float*)d_in[6];
    const float* Wsb  = (const float*)d_in[7];
    const float* whs  = (const float*)d_in[8];
    const float* whc  = (const float*)d_in[9];
    float* out = (float*)d_out;
    (void)in_sizes; (void)n_in; (void)out_size; (void)ws_size;

    float* ws = (float*)d_ws;
    size_t off = 0;
    auto take = [&](size_t n) { float* p = ws + off; off += n; return p; };
    float*  Ls    = take(8421376);
    float*  Lc    = take(8421376);
    float*  xnrow = take(32768);
    float*  xncol = take(32768);
    float*  lgs   = take(32768);
    float*  lgc   = take(32768);
    float*  co_s  = take(8224);
    float*  co_c  = take(8224);
    ushort* Ls_bf = (ushort*)take(4718592);
    ushort* Lc_bf = (ushort*)take(4718592);
    ushort* Wl_bf = (ushort*)take(36864);
    ushort* Ws_bf = (ushort*)take(18432);
    ushort* Wc_bf = (ushort*)take(18432);
    float*  part_cn   = take(1048576);   // colnorm partials 32*8*4096
    float*  part_cent = take(135168);    // centroid partials 64*8*264
    float*  F     = take(33554432);      // total 61,239,360 fl = 245.0 MiB

    // Phase overlays in F (float offsets)
    ushort* Lmat_bf = (ushort*)F;                 // [P3-P5] 16,777,216 fl
    ushort* Llin_bf = (ushort*)(F + 16777216);    // [P2-P3] 4,718,592 fl
    float*  Llin_sp = F + 21495808;               // [P2]    8,388,608 fl
    float*  ytmp    = F + 16777216;               // [P4]    4,194,304 fl
    float*  HsA     = F + 20971520;               // [P4-P5] 4,194,304 fl
    float*  HcA     = F + 25165824;               // [P4-P5] 4,194,304 fl
    ushort* HsA_bf  = (ushort*)(F + 29360128);    // [P4-P5] 2,097,152 fl
    ushort* HcA_bf  = (ushort*)(F + 31457280);    // [P4-P5] 2,097,152 fl
    float*  mx      = F + 16777216;               // [P5]    4,194,304 fl (= ytmp slot)
    ushort* Xin_bf  = (ushort*)F;                 // [P1] 4,194,304 fl
    ushort* ZT_bf   = (ushort*)(F + 4194304);     // [P1] 8,388,608 fl (b,256j,2048m)
    ushort* CS1     = (ushort*)(F + 12582912);    // [P1] 1,048,576 fl
    ushort* C2_bf   = (ushort*)(F + 13631488);    // [P1] 32,768 fl
    ushort* S2_bf   = (ushort*)(F + 13664256);    // [P1] 32,768 fl
    float*  Yst     = F + 13697024;               // [P1] 8,388,608 fl

    float* AsOut = out + 16416;
    float* AcOut = out + 16416 + 32768;

    dim3 blk(256);

    // constants
    gen_cs1<<<4096, 256, 0, stream>>>(CS1);
    gen_c2s2<<<256, 256, 0, stream>>>(C2_bf, S2_bf);
    wprep_kernel<<<512, 320, 0, stream>>>(WlW, WsW, WcW, Wl_bf, Ws_bf, Wc_bf);

    // ---- sentence: fft2.real -> e2l -> Ls ----
    // stage-1 emits Z^T via symmetry: ZT[j,m] = sum_d C2[j,d] * X[m,d]  (pure TN)
    cvt_bf_kernel<<<8192, 256, 0, stream>>>(sent, Xin_bf, 8388608);
    mfma_gemm<false,false,true,false><<<dim3(8,2,32), blk, 0, stream>>>(
        (const short*)C2_bf,256,0, (const short*)Xin_bf,256,262144, ZT_bf,2048,524288, nullptr, 256,1024,256);
    mfma_gemm<false,false,true,false><<<dim3(8,2,32), blk, 0, stream>>>(
        (const short*)S2_bf,256,0, (const short*)Xin_bf,256,262144, ZT_bf+1024,2048,524288, nullptr, 256,1024,256);
    // stage-2: Y[n,j] = sum_m CS1[n,m] * ZT[j,m]  (pure TN, K=2048)
    mfma_gemm<false,false,false,false><<<dim3(2,8,32), blk, 0, stream>>>(
        (const short*)CS1,2048,0, (const short*)ZT_bf,2048,524288, Yst,256,262144, nullptr, 1024,256,2048);
    e2l_kernel<<<32768, 256, 0, stream>>>(Yst, Ls, Ls_bf);

    // ---- comment: p_logmap0 -> fft2.real -> e2l -> Lc ----
    plog_kernel<<<32768, 256, 0, stream>>>(comm, Xin_bf);
    mfma_gemm<false,false,true,false><<<dim3(8,2,32), blk, 0, stream>>>(
        (const short*)C2_bf,256,0, (const short*)Xin_bf,256,262144, ZT_bf,2048,524288, nullptr, 256,1024,256);
    mfma_gemm<false,false,true,false><<<dim3(8,2,32), blk, 0, stream>>>(
        (const short*)S2_bf,256,0, (const short*)Xin_bf,256,262144, ZT_bf+1024,2048,524288, nullptr, 256,1024,256);
    mfma_gemm<false,false,false,false><<<dim3(2,8,32), blk, 0, stream>>>(
        (const short*)CS1,2048,0, (const short*)ZT_bf,2048,524288, Yst,256,262144, nullptr, 1024,256,2048);
    e2l_kernel<<<32768, 256, 0, stream>>>(Yst, Lc, Lc_bf);

    // ---- L = lorentz_linear(Lc, Wl): space cols only ----
    mfma_gemm<false,false,false,true><<<dim3(2,256,1), blk, 0, stream>>>(
        (const short*)Lc_bf,KPAD,0, (const short*)Wl_bf,KPAD,0, Llin_sp,256,0, Wlb+1, 32768,256,KPAD);
    lfix2_kernel<<<32768, 256, 0, stream>>>(Llin_sp, Llin_bf);

    // ---- Lmat = lorentz_act(einsum(Ls, Llin)) in bf16 ----
    mfma_gemm<false,false,true,false><<<dim3(8,8,32), blk, 0, stream>>>(
        (const short*)Ls_bf,KPAD,294912, (const short*)Llin_bf,KPAD,294912, Lmat_bf,1024,1048576, nullptr, 1024,1024,KPAD);
    lact_kernel<<<32768, 256, 0, stream>>>(Lmat_bf, xnrow);
    colnormA_kernel<<<dim3(32,8), 256, 0, stream>>>(Lmat_bf, part_cn);
    colnormB_kernel<<<dim3(32,4), 256, 0, stream>>>(part_cn, xncol);

    // ---- Hs_a / Hc_a ----
    mfma_gemm<false,false,false,true><<<dim3(1,256,1), blk, 0, stream>>>(
        (const short*)Ls_bf,KPAD,0, (const short*)Ws_bf,KPAD,0, ytmp,128,0, Wsb+1, 32768,128,KPAD);
    poinc2_kernel<<<32768, 128, 0, stream>>>(ytmp, HsA, HsA_bf);
    mfma_gemm<false,false,false,true><<<dim3(1,256,1), blk, 0, stream>>>(
        (const short*)Lc_bf,KPAD,0, (const short*)Wc_bf,KPAD,0, ytmp,128,0, Wcb+1, 32768,128,KPAD);
    poinc2_kernel<<<32768, 128, 0, stream>>>(ytmp, HcA, HcA_bf);

    // ---- Hs path: mx_s = Lmat . Hc_a ----
    mfma_gemm<false,true,false,false><<<dim3(1,8,32), blk, 0, stream>>>(
        (const short*)Lmat_bf,1024,1048576, (const short*)HcA_bf,128,131072, mx,128,131072, nullptr, 1024,128,1024);
    rowops_s_kernel<<<32768, 64, 0, stream>>>(HsA, mx, xnrow, whs, lgs);

    // ---- Hc path: mx_cT = Hs_a^T . Lmat ----
    mfma_gemm<true,true,false,false><<<dim3(8,1,32), blk, 0, stream>>>(
        (const short*)HsA_bf,128,131072, (const short*)Lmat_bf,1024,1048576, mx,1024,131072, nullptr, 128,1024,1024);
    colscale_kernel<<<dim3(32,4), 256, 0, stream>>>(mx, xncol);
    rowops_c_kernel<<<4096, 256, 0, stream>>>(HcA, mx);
    logitsc_kernel<<<dim3(32,4), 256, 0, stream>>>(mx, whc, lgc);

    // ---- softmaxes / centroids / concat ----
    softmax_kernel<<<32, 256, 0, stream>>>(lgs, AsOut);
    softmax_kernel<<<32, 256, 0, stream>>>(lgc, AcOut);
    centroidA_kernel<<<dim3(32,2,8), 320, 0, stream>>>(Ls, Lc, AsOut, AcOut, part_cent);
    centroidB_kernel<<<dim3(32,2), 320, 0, stream>>>(part_cent, co_s, co_c);
    final_kernel<<<32, 256, 0, stream>>>(co_s, co_c, out);
}